// Round 11
// baseline (960.603 us; speedup 1.0000x reference)
//
#include <hip/hip_runtime.h>

// ---------------------------------------------------------------------------
// NGCF forward, algebraically refactored:
//   per layer: S[v] = sum_{e: dst=v} w_e * x[src_e],  c[v] = sum w_e
//   out[v] = leakyrelu( (S+x)@W1 + (x*S)@W2 + (c+1)*b1 + c*b2 ), row-L2-norm
//   xui[b] = sum_l dot(x_l[user_b], x_l[NUM_USERS+pos_b])
// Round-10 post-mortem: occupancy pinned at 31% for BOTH grid 768 and 1536
// -> VGPR-capped (84 arch + 128 weight regs ~= 212 -> 2 waves/SIMD).
// This version evicts W1/W2 from VGPRs into LDS (transposed + XOR-swizzled,
// conflict-free b128 column reads), 512-thread blocks share the 32KB weights,
// and each wave batches 4 nodes per iteration so each weight read feeds 4
// nodes (LDS weight traffic 8KB/node instead of 32KB).
// ---------------------------------------------------------------------------

#define SCAN_TILE 4096   // 256 threads x 16 elems
#define LAYER_BLOCKS 768 // x 512 thr = 3 blocks/CU (LDS-capped), 24 waves/CU

__global__ __launch_bounds__(256) void init_x_kernel(
    const float* __restrict__ Gu, const float* __restrict__ Gi,
    float* __restrict__ x, int nu4, int nt4) {
  int i = blockIdx.x * 256 + threadIdx.x;
  if (i >= nt4) return;
  float4 v = (i < nu4) ? ((const float4*)Gu)[i] : ((const float4*)Gi)[i - nu4];
  ((float4*)x)[i] = v;
}

__global__ __launch_bounds__(256) void hist_kernel(
    const int* __restrict__ dst, int* __restrict__ counts, int E) {
  int e = blockIdx.x * 256 + threadIdx.x;
  if (e >= E) return;
  atomicAdd(&counts[dst[e]], 1);
}

// phase 1: per-tile sums
__global__ __launch_bounds__(256) void tile_sum_kernel(
    const int* __restrict__ counts, int* __restrict__ tsum, int n) {
  int tid = threadIdx.x;
  int lo = blockIdx.x * SCAN_TILE + tid * 16;
  int s = 0;
  if (lo + 16 <= n) {
    const int4* p = (const int4*)(counts + lo);
#pragma unroll
    for (int q = 0; q < 4; ++q) {
      int4 v = p[q];
      s += v.x + v.y + v.z + v.w;
    }
  } else {
    for (int i = lo; i < n && i < lo + 16; ++i) s += counts[i];
  }
#pragma unroll
  for (int m = 1; m < 64; m <<= 1) s += __shfl_xor(s, m, 64);
  __shared__ int red[4];
  if ((tid & 63) == 0) red[tid >> 6] = s;
  __syncthreads();
  if (tid == 0) tsum[blockIdx.x] = red[0] + red[1] + red[2] + red[3];
}

// phase 2: exclusive scan of tile sums (ntiles <= 64 -> one wave)
__global__ __launch_bounds__(64) void tile_scan_kernel(int* __restrict__ tsum,
                                                       int ntiles) {
  int lane = threadIdx.x;
  if (ntiles <= 64) {
    int v = (lane < ntiles) ? tsum[lane] : 0;
    int incl = v;
#pragma unroll
    for (int m = 1; m < 64; m <<= 1) {
      int t = __shfl_up(incl, m, 64);
      if (lane >= m) incl += t;
    }
    if (lane < ntiles) tsum[lane] = incl - v;
  } else if (lane == 0) {  // fallback, not expected at these sizes
    int run = 0;
    for (int i = 0; i < ntiles; ++i) {
      int t = tsum[i];
      tsum[i] = run;
      run += t;
    }
  }
}

// phase 3: per-tile exclusive scan + global offset -> starts, cursor
__global__ __launch_bounds__(256) void tile_write_kernel(
    const int* __restrict__ counts, const int* __restrict__ tsum,
    int* __restrict__ starts, int* __restrict__ cursor, int n) {
  int tid = threadIdx.x;
  int lo = blockIdx.x * SCAN_TILE + tid * 16;
  int c[16];
  int s = 0;
#pragma unroll
  for (int q = 0; q < 16; ++q) {
    int i = lo + q;
    int v = (i < n) ? counts[i] : 0;
    c[q] = v;
    s += v;
  }
  __shared__ int bs[256];
  bs[tid] = s;
  __syncthreads();
  int incl = s;
  for (int off = 1; off < 256; off <<= 1) {
    int t = (tid >= off) ? bs[tid - off] : 0;
    __syncthreads();
    incl += t;
    bs[tid] = incl;
    __syncthreads();
  }
  int run = tsum[blockIdx.x] + incl - s;
#pragma unroll
  for (int q = 0; q < 16; ++q) {
    int i = lo + q;
    if (i < n) {
      starts[i] = run;
      cursor[i] = run;
      run += c[q];
    }
  }
}

// pack {src, w-bits} into one 8B record
__global__ __launch_bounds__(256) void place_kernel(
    const int* __restrict__ src, const int* __restrict__ dst,
    const float* __restrict__ w, int* __restrict__ cursor,
    int2* __restrict__ ebuf, int E) {
  int e = blockIdx.x * 256 + threadIdx.x;
  if (e >= E) return;
  int p = atomicAdd(&cursor[dst[e]], 1);
  ebuf[p] = make_int2(src[e], __float_as_int(w[e]));
}

// one wave per batch element; lane = dim; accumulate per-layer dot into out
__global__ __launch_bounds__(256) void dot_kernel(
    const float* __restrict__ x, const int* __restrict__ user,
    const int* __restrict__ pos, float* __restrict__ out,
    int batch, int nusers, int accumulate) {
  int b = blockIdx.x * 4 + (threadIdx.x >> 6);
  int lane = threadIdx.x & 63;
  if (b >= batch) return;
  int u = user[b];
  int p = nusers + pos[b];
  float val = x[u * 64 + lane] * x[p * 64 + lane];
#pragma unroll
  for (int m = 1; m < 64; m <<= 1) val += __shfl_xor(val, m, 64);
  if (lane == 0) out[b] = accumulate ? (out[b] + val) : val;
}

// fused layer: W1/W2 in LDS (transposed, XOR-swizzled b128 chunks), 8 waves
// per block share them; each wave gathers 4 nodes then runs a batched matvec.
__global__ __launch_bounds__(512, 4) void layer_kernel(
    const float* __restrict__ xc, float* __restrict__ xn,
    const float* __restrict__ W1g, const float* __restrict__ b1,
    const float* __restrict__ W2g, const float* __restrict__ b2,
    const int* __restrict__ starts, const int* __restrict__ degs,
    const int2* __restrict__ ebuf, int nnodes) {
  const int lane = threadIdx.x & 63;
  const int wid = threadIdx.x >> 6;  // 0..7
  __shared__ float wlds[2][4096];    // [mtx][k*64 + swz(q,k)*4 + i] = W[4q+i][k]
  __shared__ float ash[8][4][64];
  __shared__ float gsh[8][4][64];

  // ---- stage W1,W2 transposed + swizzled (one-time per block) ----
  {
    const int k = threadIdx.x >> 3;      // column 0..63
    const int r = threadIdx.x & 7;       // 2 chunks each
#pragma unroll
    for (int mtx = 0; mtx < 2; ++mtx) {
      const float* Wg = mtx ? W2g : W1g;
#pragma unroll
      for (int qq = 0; qq < 2; ++qq) {
        int q = r * 2 + qq;
        float4 val;
        val.x = Wg[(4 * q + 0) * 64 + k];
        val.y = Wg[(4 * q + 1) * 64 + k];
        val.z = Wg[(4 * q + 2) * 64 + k];
        val.w = Wg[(4 * q + 3) * 64 + k];
        *(float4*)&wlds[mtx][k * 64 + ((q ^ (k & 15)) << 2)] = val;
      }
    }
  }
  const float b1k = b1[lane];
  const float b2k = b2[lane];
  __syncthreads();

  const int wstride = LAYER_BLOCKS * 8 * 4;
  for (int vbase = (blockIdx.x * 8 + wid) * 4; vbase < nnodes;
       vbase += wstride) {
    const int nv = min(4, nnodes - vbase);
    float wsum[4];

    // ---- gather phase: 4 nodes sequentially (readlane-broadcast scheme) ----
    for (int n = 0; n < nv; ++n) {
      const int v = vbase + n;
      const float xk = xc[v * 64 + lane];
      int s0 = __builtin_amdgcn_readfirstlane(starts[v]);
      int dg = __builtin_amdgcn_readfirstlane(degs[v]);
      int nl = dg < 64 ? dg : 64;

      int myidx = 0;
      float myw = 0.f;
      if (lane < nl) {
        int2 m = ebuf[s0 + lane];
        myidx = m.x << 6;
        myw = __int_as_float(m.y);
      }
      float ws = myw;
#pragma unroll
      for (int m = 1; m < 64; m <<= 1) ws += __shfl_xor(ws, m, 64);

      float S = 0.f;
      int j = 0;
      for (; j + 8 <= nl; j += 8) {
        float vv[8], ww[8];
#pragma unroll
        for (int q = 0; q < 8; ++q) {
          int a = __builtin_amdgcn_readlane(myidx, j + q);  // scalar addr
          ww[q] = __uint_as_float(
              __builtin_amdgcn_readlane(__float_as_uint(myw), j + q));
          vv[q] = xc[a + lane];  // 8 independent gathers in flight
        }
#pragma unroll
        for (int q = 0; q < 8; ++q) S = fmaf(ww[q], vv[q], S);
      }
      for (; j < nl; ++j) {
        int a = __builtin_amdgcn_readlane(myidx, j);
        float w = __uint_as_float(
            __builtin_amdgcn_readlane(__float_as_uint(myw), j));
        S = fmaf(w, xc[a + lane], S);
      }
      for (int e = s0 + 64; e < s0 + dg; ++e) {  // rare deg>64 tail
        int2 m = ebuf[e];
        float w = __int_as_float(m.y);
        ws += w;
        S = fmaf(w, xc[(m.x << 6) + lane], S);
      }
      wsum[n] = ws;
      ash[wid][n][lane] = S + xk;
      gsh[wid][n][lane] = S * xk;
    }
    asm volatile("" ::: "memory");  // order LDS writes before reads (same wave)

    // ---- batched matvec: each weight b128 read feeds 4 nodes ----
    float acc1[4] = {0.f, 0.f, 0.f, 0.f};
    float acc2[4] = {0.f, 0.f, 0.f, 0.f};
    const int swzbase = lane * 64;
    const int ksw = lane & 15;
#pragma unroll 4
    for (int q = 0; q < 16; ++q) {
      float4 w1q, w2q, av, gv;
      __builtin_memcpy(&w1q, &wlds[0][swzbase + ((q ^ ksw) << 2)], 16);
      __builtin_memcpy(&w2q, &wlds[1][swzbase + ((q ^ ksw) << 2)], 16);
#pragma unroll
      for (int n = 0; n < 4; ++n) {
        __builtin_memcpy(&av, &ash[wid][n][4 * q], 16);  // broadcast reads
        __builtin_memcpy(&gv, &gsh[wid][n][4 * q], 16);
        acc1[n] = fmaf(av.x, w1q.x, acc1[n]);
        acc1[n] = fmaf(av.y, w1q.y, acc1[n]);
        acc1[n] = fmaf(av.z, w1q.z, acc1[n]);
        acc1[n] = fmaf(av.w, w1q.w, acc1[n]);
        acc2[n] = fmaf(gv.x, w2q.x, acc2[n]);
        acc2[n] = fmaf(gv.y, w2q.y, acc2[n]);
        acc2[n] = fmaf(gv.z, w2q.z, acc2[n]);
        acc2[n] = fmaf(gv.w, w2q.w, acc2[n]);
      }
    }

    // ---- epilogue per node: bias, leaky-relu, L2 normalize, store ----
#pragma unroll
    for (int n = 0; n < 4; ++n) {
      if (n >= nv) break;
      const float cv = wsum[n];
      float pre = acc1[n] + acc2[n] + (cv + 1.0f) * b1k + cv * b2k;
      float o = (pre > 0.0f) ? pre : 0.01f * pre;  // leaky relu, slope 0.01
      float ss = o * o;
#pragma unroll
      for (int m = 1; m < 64; m <<= 1) ss += __shfl_xor(ss, m, 64);
      float nrm = sqrtf(ss);
      xn[(vbase + n) * 64 + lane] = o / fmaxf(nrm, 1e-12f);
    }
  }
}

extern "C" void kernel_launch(void* const* d_in, const int* in_sizes, int n_in,
                              void* d_out, int out_size, void* d_ws, size_t ws_size,
                              hipStream_t stream) {
  const float* Gu = (const float*)d_in[0];
  const float* Gi = (const float*)d_in[1];
  const float* W1 = (const float*)d_in[2];
  const float* b1 = (const float*)d_in[3];
  const float* W2 = (const float*)d_in[4];
  const float* b2 = (const float*)d_in[5];
  const float* ew = (const float*)d_in[6];
  const int* esrc = (const int*)d_in[7];
  const int* edst = (const int*)d_in[8];
  const int* user = (const int*)d_in[9];
  const int* pos = (const int*)d_in[10];
  float* out = (float*)d_out;

  const int NU = in_sizes[0] / 64;
  const int NI = in_sizes[1] / 64;
  const int N = NU + NI;
  const int E = in_sizes[6];
  const int B = in_sizes[9];

  char* ws = (char*)d_ws;
  size_t off = 0;
  auto carve = [&](size_t bytes) -> void* {
    void* p = ws + off;
    off = (off + bytes + 255) & ~(size_t)255;
    return p;
  };
  float* x0 = (float*)carve((size_t)N * 64 * 4);
  float* x1 = (float*)carve((size_t)N * 64 * 4);
  int2* ebuf = (int2*)carve((size_t)E * 8);
  int* startsA = (int*)carve((size_t)N * 4);
  int* cursor = (int*)carve((size_t)N * 4);
  int* counts = (int*)carve((size_t)N * 4);
  const int ntiles = (N + SCAN_TILE - 1) / SCAN_TILE;
  int* tsum = (int*)carve((size_t)ntiles * 4);

  hipMemsetAsync(counts, 0, (size_t)N * 4, stream);

  hist_kernel<<<(E + 255) / 256, 256, 0, stream>>>(edst, counts, E);
  tile_sum_kernel<<<ntiles, 256, 0, stream>>>(counts, tsum, N);
  tile_scan_kernel<<<1, 64, 0, stream>>>(tsum, ntiles);
  tile_write_kernel<<<ntiles, 256, 0, stream>>>(counts, tsum, startsA, cursor, N);
  place_kernel<<<(E + 255) / 256, 256, 0, stream>>>(esrc, edst, ew, cursor, ebuf, E);

  int nt4 = N * 64 / 4;
  int nu4 = NU * 64 / 4;
  init_x_kernel<<<(nt4 + 255) / 256, 256, 0, stream>>>(Gu, Gi, x0, nu4, nt4);
  dot_kernel<<<(B + 3) / 4, 256, 0, stream>>>(x0, user, pos, out, B, NU, 0);

  float* xc = x0;
  float* xn = x1;
  for (int l = 0; l < 3; ++l) {
    layer_kernel<<<LAYER_BLOCKS, 512, 0, stream>>>(xc, xn, W1 + l * 4096,
                                                   b1 + l * 64, W2 + l * 4096,
                                                   b2 + l * 64, startsA, counts,
                                                   ebuf, N);
    dot_kernel<<<(B + 3) / 4, 256, 0, stream>>>(xn, user, pos, out, B, NU, 1);
    float* t = xc;
    xc = xn;
    xn = t;
  }
}